// Round 1
// baseline (452.111 us; speedup 1.0000x reference)
//
#include <hip/hip_runtime.h>

// Problem constants (from reference setup_inputs)
constexpr int GRID_D = 128;
constexpr int BATCHN = 4;
constexpr int C = 64;
constexpr int VOL = GRID_D * GRID_D * GRID_D;      // 2,097,152
constexpr int V = BATCHN * VOL;                    // 8,388,608 voxel ids
constexpr int W = V / 32;                          // 262,144 bitmask words
constexpr int SCAN_BS = 1024;                      // threads per scan block
constexpr int SCAN_NB = W / SCAN_BS;               // 256 scan blocks

// ---------------- kernels ----------------

// Fill the unique-id region with -1.0f
__global__ void fill_neg1(float* out, int n) {
    int i = blockIdx.x * blockDim.x + threadIdx.x;
    if (i < n) out[i] = -1.0f;
}

// Mark each point's voxel id in the bitmask
__global__ void mark_bits(const int* __restrict__ coords, unsigned* __restrict__ bm, int n) {
    int i = blockIdx.x * blockDim.x + threadIdx.x;
    if (i >= n) return;
    int4 co = reinterpret_cast<const int4*>(coords)[i];
    int lin = co.w * VOL + co.x * (GRID_D * GRID_D) + co.y * GRID_D + co.z;
    atomicOr(&bm[lin >> 5], 1u << (lin & 31));
}

// Level-1 scan: per-block exclusive scan of popcounts; block totals out
__global__ void scan1(const unsigned* __restrict__ bm, unsigned* __restrict__ wp,
                      unsigned* __restrict__ bs) {
    int idx = blockIdx.x * SCAN_BS + threadIdx.x;
    unsigned pc = __popc(bm[idx]);
    unsigned v = pc;
    // wave-64 inclusive scan
    #pragma unroll
    for (int d = 1; d < 64; d <<= 1) {
        unsigned t = __shfl_up(v, d, 64);
        if ((threadIdx.x & 63) >= d) v += t;
    }
    __shared__ unsigned wsum[16];
    int wid = threadIdx.x >> 6;
    int lane = threadIdx.x & 63;
    if (lane == 63) wsum[wid] = v;
    __syncthreads();
    if (threadIdx.x < 16) {
        unsigned s = wsum[threadIdx.x];
        #pragma unroll
        for (int d = 1; d < 16; d <<= 1) {
            unsigned t = __shfl_up(s, d, 16);
            if ((threadIdx.x & 15) >= d) s += t;
        }
        wsum[threadIdx.x] = s;  // inclusive wave totals
    }
    __syncthreads();
    unsigned waveoff = (wid == 0) ? 0u : wsum[wid - 1];
    wp[idx] = waveoff + v - pc;                       // exclusive within block
    if (threadIdx.x == SCAN_BS - 1) bs[blockIdx.x] = waveoff + v;  // block total
}

// Level-2 scan: exclusive scan of the 256 block totals, in place
__global__ void scan2(unsigned* bs) {
    int t = threadIdx.x;  // 256 threads
    unsigned pc = bs[t];
    unsigned v = pc;
    #pragma unroll
    for (int d = 1; d < 64; d <<= 1) {
        unsigned tt = __shfl_up(v, d, 64);
        if ((t & 63) >= d) v += tt;
    }
    __shared__ unsigned wsum[4];
    int wid = t >> 6, lane = t & 63;
    if (lane == 63) wsum[wid] = v;
    __syncthreads();
    if (t < 4) {
        unsigned s = wsum[t];
        #pragma unroll
        for (int d = 1; d < 4; d <<= 1) {
            unsigned tt = __shfl_up(s, d, 4);
            if ((t & 3) >= d) s += tt;
        }
        wsum[t] = s;
    }
    __syncthreads();
    unsigned waveoff = (wid == 0) ? 0u : wsum[wid - 1];
    bs[t] = waveoff + v - pc;  // exclusive block offsets
}

// Add block offsets so wp[] becomes a global exclusive word-prefix
__global__ void add_offsets(unsigned* __restrict__ wp, const unsigned* __restrict__ bs) {
    int idx = blockIdx.x * blockDim.x + threadIdx.x;
    wp[idx] += bs[idx >> 10];
}

// Emit sorted unique ids (as float) at their ranks
__global__ void emit_uniq(const unsigned* __restrict__ bm, const unsigned* __restrict__ wp,
                          float* __restrict__ out) {
    int idx = blockIdx.x * blockDim.x + threadIdx.x;
    unsigned word = bm[idx];
    unsigned base = wp[idx];
    while (word) {
        int b = __ffs(word) - 1;
        out[base++] = (float)((idx << 5) + b);
        word &= word - 1;
    }
}

// Scatter-sum features: one thread per (point, channel)
__global__ void scatter_feat(const int* __restrict__ coords, const float* __restrict__ feat,
                             const unsigned* __restrict__ bm, const unsigned* __restrict__ wp,
                             float* __restrict__ outf, int n) {
    int gid = blockIdx.x * blockDim.x + threadIdx.x;
    int pt = gid >> 6;
    int c = gid & 63;
    if (pt >= n) return;
    int4 co = reinterpret_cast<const int4*>(coords)[pt];
    int lin = co.w * VOL + co.x * (GRID_D * GRID_D) + co.y * GRID_D + co.z;
    int w = lin >> 5, b = lin & 31;
    unsigned rank = wp[w] + __popc(bm[w] & ((1u << b) - 1u));
    atomicAdd(&outf[(size_t)rank * C + c], feat[(size_t)pt * C + c]);
}

// ---------------- launch ----------------

extern "C" void kernel_launch(void* const* d_in, const int* in_sizes, int n_in,
                              void* d_out, int out_size, void* d_ws, size_t ws_size,
                              hipStream_t stream) {
    const int* coords = (const int*)d_in[0];
    const float* feat = (const float*)d_in[1];
    int n = in_sizes[0] / 4;  // N points

    float* out_ids = (float*)d_out;            // [n] unique ids (float), -1 padded
    float* out_feat = (float*)d_out + n;       // [n][C] scattered features

    unsigned* bm = (unsigned*)d_ws;            // bitmask, W words
    unsigned* wp = bm + W;                     // word prefix, W words
    unsigned* bs = wp + W;                     // block sums, SCAN_NB words

    // zero bitmask + feature output region (atomics accumulate onto these)
    hipMemsetAsync(bm, 0, (size_t)W * sizeof(unsigned), stream);
    hipMemsetAsync(out_feat, 0, (size_t)n * C * sizeof(float), stream);

    fill_neg1<<<(n + 255) / 256, 256, 0, stream>>>(out_ids, n);
    mark_bits<<<(n + 255) / 256, 256, 0, stream>>>(coords, bm, n);
    scan1<<<SCAN_NB, SCAN_BS, 0, stream>>>(bm, wp, bs);
    scan2<<<1, SCAN_NB, 0, stream>>>(bs);
    add_offsets<<<W / 1024, 1024, 0, stream>>>(wp, bs);
    emit_uniq<<<W / 256, 256, 0, stream>>>(bm, wp, out_ids);

    int scatter_threads = n * C;
    scatter_feat<<<(scatter_threads + 255) / 256, 256, 0, stream>>>(coords, feat, bm, wp,
                                                                    out_feat, n);
}

// Round 2
// 243.995 us; speedup vs baseline: 1.8530x; 1.8530x over previous
//
#include <hip/hip_runtime.h>

// Problem constants (from reference setup_inputs)
constexpr int GRID_D = 128;
constexpr int BATCHN = 4;
constexpr int C = 64;
constexpr int VOL = GRID_D * GRID_D * GRID_D;      // 2,097,152
constexpr int V = BATCHN * VOL;                    // 8,388,608 voxel ids
constexpr int W = V / 32;                          // 262,144 bitmask words
constexpr int SCAN_BS = 1024;                      // threads per scan block
constexpr int SCAN_NB = W / SCAN_BS;               // 256 scan blocks

// ---------------- kernels ----------------

// Fill the unique-id region with -1.0f
__global__ void fill_neg1(float* out, int n) {
    int i = blockIdx.x * blockDim.x + threadIdx.x;
    if (i < n) out[i] = -1.0f;
}

// Mark each point's voxel id in the bitmask; second hit marks the dup bitmap.
__global__ void mark_bits(const int* __restrict__ coords, unsigned* __restrict__ bm,
                          unsigned* __restrict__ dup, int n) {
    int i = blockIdx.x * blockDim.x + threadIdx.x;
    if (i >= n) return;
    int4 co = reinterpret_cast<const int4*>(coords)[i];
    int lin = co.w * VOL + co.x * (GRID_D * GRID_D) + co.y * GRID_D + co.z;
    unsigned bit = 1u << (lin & 31);
    unsigned old = atomicOr(&bm[lin >> 5], bit);
    if (old & bit) atomicOr(&dup[lin >> 5], bit);
}

// Level-1 scan: per-block exclusive scan of popcounts; block totals out
__global__ void scan1(const unsigned* __restrict__ bm, unsigned* __restrict__ wp,
                      unsigned* __restrict__ bs) {
    int idx = blockIdx.x * SCAN_BS + threadIdx.x;
    unsigned pc = __popc(bm[idx]);
    unsigned v = pc;
    #pragma unroll
    for (int d = 1; d < 64; d <<= 1) {
        unsigned t = __shfl_up(v, d, 64);
        if ((threadIdx.x & 63) >= d) v += t;
    }
    __shared__ unsigned wsum[16];
    int wid = threadIdx.x >> 6;
    int lane = threadIdx.x & 63;
    if (lane == 63) wsum[wid] = v;
    __syncthreads();
    if (threadIdx.x < 16) {
        unsigned s = wsum[threadIdx.x];
        #pragma unroll
        for (int d = 1; d < 16; d <<= 1) {
            unsigned t = __shfl_up(s, d, 16);
            if ((threadIdx.x & 15) >= d) s += t;
        }
        wsum[threadIdx.x] = s;  // inclusive wave totals
    }
    __syncthreads();
    unsigned waveoff = (wid == 0) ? 0u : wsum[wid - 1];
    wp[idx] = waveoff + v - pc;                       // exclusive within block
    if (threadIdx.x == SCAN_BS - 1) bs[blockIdx.x] = waveoff + v;  // block total
}

// Level-2 scan: exclusive scan of the 256 block totals, in place; also emit grand total
__global__ void scan2(unsigned* bs, unsigned* total) {
    int t = threadIdx.x;  // 256 threads
    unsigned pc = bs[t];
    unsigned v = pc;
    #pragma unroll
    for (int d = 1; d < 64; d <<= 1) {
        unsigned tt = __shfl_up(v, d, 64);
        if ((t & 63) >= d) v += tt;
    }
    __shared__ unsigned wsum[4];
    int wid = t >> 6, lane = t & 63;
    if (lane == 63) wsum[wid] = v;
    __syncthreads();
    if (t < 4) {
        unsigned s = wsum[t];
        #pragma unroll
        for (int d = 1; d < 4; d <<= 1) {
            unsigned tt = __shfl_up(s, d, 4);
            if ((t & 3) >= d) s += tt;
        }
        wsum[t] = s;
    }
    __syncthreads();
    unsigned waveoff = (wid == 0) ? 0u : wsum[wid - 1];
    bs[t] = waveoff + v - pc;  // exclusive block offsets
    if (t == SCAN_NB - 1) *total = waveoff + v;  // grand total = unique count
}

// Add block offsets so wp[] becomes a global exclusive word-prefix
__global__ void add_offsets(unsigned* __restrict__ wp, const unsigned* __restrict__ bs) {
    int idx = blockIdx.x * blockDim.x + threadIdx.x;
    wp[idx] += bs[idx >> 10];
}

// Emit sorted unique ids (as float) at their ranks
__global__ void emit_uniq(const unsigned* __restrict__ bm, const unsigned* __restrict__ wp,
                          float* __restrict__ out) {
    int idx = blockIdx.x * blockDim.x + threadIdx.x;
    unsigned word = bm[idx];
    unsigned base = wp[idx];
    while (word) {
        int b = __ffs(word) - 1;
        out[base++] = (float)((idx << 5) + b);
        word &= word - 1;
    }
}

// Zero output rows of voxels with >1 contributor (they get atomicAdd'ed)
__global__ void zero_dup(const unsigned* __restrict__ bm, const unsigned* __restrict__ dup,
                         const unsigned* __restrict__ wp, float* __restrict__ outf) {
    int idx = blockIdx.x * blockDim.x + threadIdx.x;
    unsigned d = dup[idx];
    if (!d) return;
    unsigned word = bm[idx];
    unsigned base = wp[idx];
    while (d) {
        int b = __ffs(d) - 1;
        unsigned rank = base + __popc(word & ((1u << b) - 1u));
        float4* p = reinterpret_cast<float4*>(outf + (size_t)rank * C);
        #pragma unroll
        for (int i = 0; i < 16; i++) p[i] = float4{0.f, 0.f, 0.f, 0.f};
        d &= d - 1;
    }
}

// Zero output rows beyond the unique count (reference pads with zeros)
__global__ void zero_tail(float* __restrict__ outf, const unsigned* __restrict__ total, int n) {
    int gid = blockIdx.x * blockDim.x + threadIdx.x;  // one float4 per thread
    int rank = gid >> 4;
    if (rank >= n || rank < (int)*total) return;
    reinterpret_cast<float4*>(outf)[gid] = float4{0.f, 0.f, 0.f, 0.f};
}

// Scatter features: plain float4 store for singleton voxels, atomicAdd for dups.
// 16 threads per point (one float4 each) -> 4 points per wave, 256B contiguous stores.
__global__ void scatter_feat(const int* __restrict__ coords, const float4* __restrict__ feat4,
                             const unsigned* __restrict__ bm, const unsigned* __restrict__ dup,
                             const unsigned* __restrict__ wp, float* __restrict__ outf, int n) {
    int gid = blockIdx.x * blockDim.x + threadIdx.x;
    int pt = gid >> 4;
    int c4 = gid & 15;
    if (pt >= n) return;
    int4 co = reinterpret_cast<const int4*>(coords)[pt];
    int lin = co.w * VOL + co.x * (GRID_D * GRID_D) + co.y * GRID_D + co.z;
    int w = lin >> 5, b = lin & 31;
    unsigned rank = wp[w] + __popc(bm[w] & ((1u << b) - 1u));
    float4 v = feat4[(size_t)pt * 16 + c4];
    float* dst = outf + (size_t)rank * C + c4 * 4;
    if (dup[w] & (1u << b)) {
        atomicAdd(dst + 0, v.x);
        atomicAdd(dst + 1, v.y);
        atomicAdd(dst + 2, v.z);
        atomicAdd(dst + 3, v.w);
    } else {
        *reinterpret_cast<float4*>(dst) = v;
    }
}

// ---------------- launch ----------------

extern "C" void kernel_launch(void* const* d_in, const int* in_sizes, int n_in,
                              void* d_out, int out_size, void* d_ws, size_t ws_size,
                              hipStream_t stream) {
    const int* coords = (const int*)d_in[0];
    const float* feat = (const float*)d_in[1];
    int n = in_sizes[0] / 4;  // N points

    float* out_ids = (float*)d_out;            // [n] unique ids (float), -1 padded
    float* out_feat = (float*)d_out + n;       // [n][C] scattered features

    unsigned* bm = (unsigned*)d_ws;            // bitmask, W words
    unsigned* dup = bm + W;                    // duplicate bitmask, W words
    unsigned* wp = dup + W;                    // word prefix, W words
    unsigned* bs = wp + W;                     // block sums, SCAN_NB words
    unsigned* total = bs + SCAN_NB;            // grand total (unique count)

    // zero bitmask + dup bitmask (contiguous, 2 MB)
    hipMemsetAsync(bm, 0, (size_t)2 * W * sizeof(unsigned), stream);

    fill_neg1<<<(n + 255) / 256, 256, 0, stream>>>(out_ids, n);
    mark_bits<<<(n + 255) / 256, 256, 0, stream>>>(coords, bm, dup, n);
    scan1<<<SCAN_NB, SCAN_BS, 0, stream>>>(bm, wp, bs);
    scan2<<<1, SCAN_NB, 0, stream>>>(bs, total);
    add_offsets<<<W / 1024, 1024, 0, stream>>>(wp, bs);
    emit_uniq<<<W / 256, 256, 0, stream>>>(bm, wp, out_ids);
    zero_dup<<<W / 256, 256, 0, stream>>>(bm, dup, wp, out_feat);
    zero_tail<<<(n * 16 + 255) / 256, 256, 0, stream>>>(out_feat, total, n);

    int scatter_threads = n * 16;  // one float4 per thread
    scatter_feat<<<(scatter_threads + 255) / 256, 256, 0, stream>>>(
        coords, (const float4*)feat, bm, dup, wp, out_feat, n);
}

// Round 3
// 242.443 us; speedup vs baseline: 1.8648x; 1.0064x over previous
//
#include <hip/hip_runtime.h>

// Problem constants (from reference setup_inputs)
constexpr int GRID_D = 128;
constexpr int BATCHN = 4;
constexpr int C = 64;
constexpr int VOL = GRID_D * GRID_D * GRID_D;      // 2,097,152
constexpr int V = BATCHN * VOL;                    // 8,388,608 voxel ids
constexpr int W = V / 32;                          // 262,144 bitmask words
constexpr int SCAN_BS = 1024;                      // threads per scan block
constexpr int SCAN_NB = W / SCAN_BS;               // 256 scan blocks

// ---------------- kernels ----------------

// Zero the 2 MB bitmask+dup region (own kernel: rocclr fillBuffer was 158us!)
__global__ void zero_ws(uint4* __restrict__ p) {
    int i = blockIdx.x * blockDim.x + threadIdx.x;
    p[i] = uint4{0u, 0u, 0u, 0u};
}

// Fill the unique-id region with -1.0f
__global__ void fill_neg1(float* out, int n) {
    int i = blockIdx.x * blockDim.x + threadIdx.x;
    if (i < n) out[i] = -1.0f;
}

// Mark each point's voxel id in the bitmask; second hit marks the dup bitmap.
__global__ void mark_bits(const int* __restrict__ coords, unsigned* __restrict__ bm,
                          unsigned* __restrict__ dup, int n) {
    int i = blockIdx.x * blockDim.x + threadIdx.x;
    if (i >= n) return;
    int4 co = reinterpret_cast<const int4*>(coords)[i];
    int lin = co.w * VOL + co.x * (GRID_D * GRID_D) + co.y * GRID_D + co.z;
    unsigned bit = 1u << (lin & 31);
    unsigned old = atomicOr(&bm[lin >> 5], bit);
    if (old & bit) atomicOr(&dup[lin >> 5], bit);
}

// Level-1 scan: per-block exclusive scan of popcounts; block totals out
__global__ void scan1(const unsigned* __restrict__ bm, unsigned* __restrict__ wp,
                      unsigned* __restrict__ bs) {
    int idx = blockIdx.x * SCAN_BS + threadIdx.x;
    unsigned pc = __popc(bm[idx]);
    unsigned v = pc;
    #pragma unroll
    for (int d = 1; d < 64; d <<= 1) {
        unsigned t = __shfl_up(v, d, 64);
        if ((threadIdx.x & 63) >= d) v += t;
    }
    __shared__ unsigned wsum[16];
    int wid = threadIdx.x >> 6;
    int lane = threadIdx.x & 63;
    if (lane == 63) wsum[wid] = v;
    __syncthreads();
    if (threadIdx.x < 16) {
        unsigned s = wsum[threadIdx.x];
        #pragma unroll
        for (int d = 1; d < 16; d <<= 1) {
            unsigned t = __shfl_up(s, d, 16);
            if ((threadIdx.x & 15) >= d) s += t;
        }
        wsum[threadIdx.x] = s;  // inclusive wave totals
    }
    __syncthreads();
    unsigned waveoff = (wid == 0) ? 0u : wsum[wid - 1];
    wp[idx] = waveoff + v - pc;                       // exclusive within block
    if (threadIdx.x == SCAN_BS - 1) bs[blockIdx.x] = waveoff + v;  // block total
}

// Level-2 scan: exclusive scan of the 256 block totals, in place; also emit grand total
__global__ void scan2(unsigned* bs, unsigned* total) {
    int t = threadIdx.x;  // 256 threads
    unsigned pc = bs[t];
    unsigned v = pc;
    #pragma unroll
    for (int d = 1; d < 64; d <<= 1) {
        unsigned tt = __shfl_up(v, d, 64);
        if ((t & 63) >= d) v += tt;
    }
    __shared__ unsigned wsum[4];
    int wid = t >> 6, lane = t & 63;
    if (lane == 63) wsum[wid] = v;
    __syncthreads();
    if (t < 4) {
        unsigned s = wsum[t];
        #pragma unroll
        for (int d = 1; d < 4; d <<= 1) {
            unsigned tt = __shfl_up(s, d, 4);
            if ((t & 3) >= d) s += tt;
        }
        wsum[t] = s;
    }
    __syncthreads();
    unsigned waveoff = (wid == 0) ? 0u : wsum[wid - 1];
    bs[t] = waveoff + v - pc;  // exclusive block offsets
    if (t == SCAN_NB - 1) *total = waveoff + v;  // grand total = unique count
}

// Add block offsets so wp[] becomes a global exclusive word-prefix
__global__ void add_offsets(unsigned* __restrict__ wp, const unsigned* __restrict__ bs) {
    int idx = blockIdx.x * blockDim.x + threadIdx.x;
    wp[idx] += bs[idx >> 10];
}

// Emit sorted unique ids (as float) at their ranks
__global__ void emit_uniq(const unsigned* __restrict__ bm, const unsigned* __restrict__ wp,
                          float* __restrict__ out) {
    int idx = blockIdx.x * blockDim.x + threadIdx.x;
    unsigned word = bm[idx];
    unsigned base = wp[idx];
    while (word) {
        int b = __ffs(word) - 1;
        out[base++] = (float)((idx << 5) + b);
        word &= word - 1;
    }
}

// Zero output rows of voxels with >1 contributor (they get atomicAdd'ed)
__global__ void zero_dup(const unsigned* __restrict__ bm, const unsigned* __restrict__ dup,
                         const unsigned* __restrict__ wp, float* __restrict__ outf) {
    int idx = blockIdx.x * blockDim.x + threadIdx.x;
    unsigned d = dup[idx];
    if (!d) return;
    unsigned word = bm[idx];
    unsigned base = wp[idx];
    while (d) {
        int b = __ffs(d) - 1;
        unsigned rank = base + __popc(word & ((1u << b) - 1u));
        float4* p = reinterpret_cast<float4*>(outf + (size_t)rank * C);
        #pragma unroll
        for (int i = 0; i < 16; i++) p[i] = float4{0.f, 0.f, 0.f, 0.f};
        d &= d - 1;
    }
}

// Zero output rows beyond the unique count (reference pads with zeros)
__global__ void zero_tail(float* __restrict__ outf, const unsigned* __restrict__ total, int n) {
    int gid = blockIdx.x * blockDim.x + threadIdx.x;  // one float4 per thread
    int rank = gid >> 4;
    if (rank >= n || rank < (int)*total) return;
    reinterpret_cast<float4*>(outf)[gid] = float4{0.f, 0.f, 0.f, 0.f};
}

// Scatter features: plain float4 store for singleton voxels, atomicAdd for dups.
// 16 threads per point (one float4 each) -> 4 points per wave, 256B contiguous stores.
__global__ void scatter_feat(const int* __restrict__ coords, const float4* __restrict__ feat4,
                             const unsigned* __restrict__ bm, const unsigned* __restrict__ dup,
                             const unsigned* __restrict__ wp, float* __restrict__ outf, int n) {
    int gid = blockIdx.x * blockDim.x + threadIdx.x;
    int pt = gid >> 4;
    int c4 = gid & 15;
    if (pt >= n) return;
    int4 co = reinterpret_cast<const int4*>(coords)[pt];
    int lin = co.w * VOL + co.x * (GRID_D * GRID_D) + co.y * GRID_D + co.z;
    int w = lin >> 5, b = lin & 31;
    unsigned rank = wp[w] + __popc(bm[w] & ((1u << b) - 1u));
    float4 v = feat4[(size_t)pt * 16 + c4];
    float* dst = outf + (size_t)rank * C + c4 * 4;
    if (dup[w] & (1u << b)) {
        atomicAdd(dst + 0, v.x);
        atomicAdd(dst + 1, v.y);
        atomicAdd(dst + 2, v.z);
        atomicAdd(dst + 3, v.w);
    } else {
        *reinterpret_cast<float4*>(dst) = v;
    }
}

// ---------------- launch ----------------

extern "C" void kernel_launch(void* const* d_in, const int* in_sizes, int n_in,
                              void* d_out, int out_size, void* d_ws, size_t ws_size,
                              hipStream_t stream) {
    const int* coords = (const int*)d_in[0];
    const float* feat = (const float*)d_in[1];
    int n = in_sizes[0] / 4;  // N points

    float* out_ids = (float*)d_out;            // [n] unique ids (float), -1 padded
    float* out_feat = (float*)d_out + n;       // [n][C] scattered features

    unsigned* bm = (unsigned*)d_ws;            // bitmask, W words
    unsigned* dup = bm + W;                    // duplicate bitmask, W words
    unsigned* wp = dup + W;                    // word prefix, W words
    unsigned* bs = wp + W;                     // block sums, SCAN_NB words
    unsigned* total = bs + SCAN_NB;            // grand total (unique count)

    // zero bitmask + dup bitmask (2 MB) with our own kernel
    // (hipMemsetAsync -> rocclr fillBufferAligned ran at ~13 GB/s, 158 us!)
    zero_ws<<<(2 * W * 4 / 16) / 256, 256, 0, stream>>>((uint4*)bm);

    fill_neg1<<<(n + 255) / 256, 256, 0, stream>>>(out_ids, n);
    mark_bits<<<(n + 255) / 256, 256, 0, stream>>>(coords, bm, dup, n);
    scan1<<<SCAN_NB, SCAN_BS, 0, stream>>>(bm, wp, bs);
    scan2<<<1, SCAN_NB, 0, stream>>>(bs, total);
    add_offsets<<<W / 1024, 1024, 0, stream>>>(wp, bs);
    emit_uniq<<<W / 256, 256, 0, stream>>>(bm, wp, out_ids);
    zero_dup<<<W / 256, 256, 0, stream>>>(bm, dup, wp, out_feat);
    zero_tail<<<(n * 16 + 255) / 256, 256, 0, stream>>>(out_feat, total, n);

    int scatter_threads = n * 16;  // one float4 per thread
    scatter_feat<<<(scatter_threads + 255) / 256, 256, 0, stream>>>(
        coords, (const float4*)feat, bm, dup, wp, out_feat, n);
}

// Round 5
// 227.206 us; speedup vs baseline: 1.9899x; 1.0671x over previous
//
#include <hip/hip_runtime.h>

// Problem constants (from reference setup_inputs)
constexpr int GRID_D = 128;
constexpr int BATCHN = 4;
constexpr int C = 64;
constexpr int VOL = GRID_D * GRID_D * GRID_D;      // 2,097,152
constexpr int V = BATCHN * VOL;                    // 8,388,608 voxel ids
constexpr int W = V / 32;                          // 262,144 bitmask words
constexpr int SCAN_BS = 1024;                      // threads per scan block
constexpr int SCAN_NB = W / SCAN_BS;               // 256 scan blocks

// clang native vector type (works with __builtin_nontemporal_*)
typedef float floatx4 __attribute__((ext_vector_type(4)));

// ---------------- kernels ----------------

// Zero the 2 MB bitmask+dup region
__global__ void zero_ws(uint4* __restrict__ p) {
    int i = blockIdx.x * blockDim.x + threadIdx.x;
    p[i] = uint4{0u, 0u, 0u, 0u};
}

// Mark each point's voxel id in the bitmask; store lin[] for later passes;
// second hit on a bit marks the dup bitmap.
__global__ void mark_bits(const int* __restrict__ coords, unsigned* __restrict__ bm,
                          unsigned* __restrict__ dup, unsigned* __restrict__ lin,
                          int n) {
    int i = blockIdx.x * blockDim.x + threadIdx.x;
    if (i >= n) return;
    int4 co = reinterpret_cast<const int4*>(coords)[i];
    unsigned l = (unsigned)(co.w * VOL + co.x * (GRID_D * GRID_D) + co.y * GRID_D + co.z);
    lin[i] = l;
    unsigned bit = 1u << (l & 31);
    unsigned old = atomicOr(&bm[l >> 5], bit);
    if (old & bit) atomicOr(&dup[l >> 5], bit);
}

// Level-1 scan: per-block exclusive scan of popcounts (wp stays block-local);
// block totals to bs[]
__global__ void scan1(const unsigned* __restrict__ bm, unsigned* __restrict__ wp,
                      unsigned* __restrict__ bs) {
    int idx = blockIdx.x * SCAN_BS + threadIdx.x;
    unsigned pc = __popc(bm[idx]);
    unsigned v = pc;
    #pragma unroll
    for (int d = 1; d < 64; d <<= 1) {
        unsigned t = __shfl_up(v, d, 64);
        if ((threadIdx.x & 63) >= d) v += t;
    }
    __shared__ unsigned wsum[16];
    int wid = threadIdx.x >> 6;
    int lane = threadIdx.x & 63;
    if (lane == 63) wsum[wid] = v;
    __syncthreads();
    if (threadIdx.x < 16) {
        unsigned s = wsum[threadIdx.x];
        #pragma unroll
        for (int d = 1; d < 16; d <<= 1) {
            unsigned t = __shfl_up(s, d, 16);
            if ((threadIdx.x & 15) >= d) s += t;
        }
        wsum[threadIdx.x] = s;  // inclusive wave totals
    }
    __syncthreads();
    unsigned waveoff = (wid == 0) ? 0u : wsum[wid - 1];
    wp[idx] = waveoff + v - pc;                       // exclusive within block
    if (threadIdx.x == SCAN_BS - 1) bs[blockIdx.x] = waveoff + v;  // block total
}

// Level-2 scan: exclusive scan of the 256 block totals in place; grand total -> bs[256]
__global__ void scan2(unsigned* bs) {
    int t = threadIdx.x;  // 256 threads
    unsigned pc = bs[t];
    unsigned v = pc;
    #pragma unroll
    for (int d = 1; d < 64; d <<= 1) {
        unsigned tt = __shfl_up(v, d, 64);
        if ((t & 63) >= d) v += tt;
    }
    __shared__ unsigned wsum[4];
    int wid = t >> 6, lane = t & 63;
    if (lane == 63) wsum[wid] = v;
    __syncthreads();
    if (t < 4) {
        unsigned s = wsum[t];
        #pragma unroll
        for (int d = 1; d < 4; d <<= 1) {
            unsigned tt = __shfl_up(s, d, 4);
            if ((t & 3) >= d) s += tt;
        }
        wsum[t] = s;
    }
    __syncthreads();
    unsigned waveoff = (wid == 0) ? 0u : wsum[wid - 1];
    bs[t] = waveoff + v - pc;          // exclusive block offsets
    if (t == SCAN_NB - 1) bs[SCAN_NB] = waveoff + v;  // grand total = unique count
}

// Emit sorted unique ids (as float) at their ranks
__global__ void emit_uniq(const unsigned* __restrict__ bm, const unsigned* __restrict__ wp,
                          const unsigned* __restrict__ bs, float* __restrict__ out) {
    int idx = blockIdx.x * blockDim.x + threadIdx.x;
    unsigned word = bm[idx];
    unsigned base = wp[idx] + bs[idx >> 10];
    while (word) {
        int b = __ffs(word) - 1;
        out[base++] = (float)((idx << 5) + b);
        word &= word - 1;
    }
}

// Tail: ids[rank] = -1 and feature rows = 0 for rank in [total, n)
__global__ void tail_fill(float* __restrict__ out_ids, float* __restrict__ outf,
                          const unsigned* __restrict__ bs, int n) {
    int gid = blockIdx.x * blockDim.x + threadIdx.x;  // one float4 per thread
    int rank = gid >> 4;
    unsigned total = bs[SCAN_NB];
    if (rank >= n || rank < (int)total) return;
    reinterpret_cast<float4*>(outf)[gid] = float4{0.f, 0.f, 0.f, 0.f};
    if ((gid & 15) == 0) out_ids[rank] = -1.0f;
}

// Zero output rows of voxels with >1 contributor (they get atomicAdd'ed)
__global__ void zero_dup(const unsigned* __restrict__ bm, const unsigned* __restrict__ dup,
                         const unsigned* __restrict__ wp, const unsigned* __restrict__ bs,
                         float* __restrict__ outf) {
    int idx = blockIdx.x * blockDim.x + threadIdx.x;
    unsigned d = dup[idx];
    if (!d) return;
    unsigned word = bm[idx];
    unsigned base = wp[idx] + bs[idx >> 10];
    while (d) {
        int b = __ffs(d) - 1;
        unsigned rank = base + __popc(word & ((1u << b) - 1u));
        float4* p = reinterpret_cast<float4*>(outf + (size_t)rank * C);
        #pragma unroll
        for (int i = 0; i < 16; i++) p[i] = float4{0.f, 0.f, 0.f, 0.f};
        d &= d - 1;
    }
}

// Scatter features: plain nontemporal float4 store for singleton voxels,
// atomicAdd for dups. 16 threads per point (one float4 each).
__global__ void scatter_feat(const unsigned* __restrict__ lin, const floatx4* __restrict__ feat4,
                             const unsigned* __restrict__ bm, const unsigned* __restrict__ dup,
                             const unsigned* __restrict__ wp, const unsigned* __restrict__ bs,
                             float* __restrict__ outf, int n) {
    int gid = blockIdx.x * blockDim.x + threadIdx.x;
    int pt = gid >> 4;
    int c4 = gid & 15;
    if (pt >= n) return;
    unsigned l = lin[pt];
    unsigned w = l >> 5, b = l & 31;
    unsigned rank = wp[w] + bs[w >> 10] + __popc(bm[w] & ((1u << b) - 1u));
    floatx4 v = __builtin_nontemporal_load(&feat4[(size_t)pt * 16 + c4]);
    float* dst = outf + (size_t)rank * C + c4 * 4;
    if (dup[w] & (1u << b)) {
        atomicAdd(dst + 0, v.x);
        atomicAdd(dst + 1, v.y);
        atomicAdd(dst + 2, v.z);
        atomicAdd(dst + 3, v.w);
    } else {
        __builtin_nontemporal_store(v, reinterpret_cast<floatx4*>(dst));
    }
}

// ---------------- launch ----------------

extern "C" void kernel_launch(void* const* d_in, const int* in_sizes, int n_in,
                              void* d_out, int out_size, void* d_ws, size_t ws_size,
                              hipStream_t stream) {
    const int* coords = (const int*)d_in[0];
    const float* feat = (const float*)d_in[1];
    int n = in_sizes[0] / 4;  // N points

    float* out_ids = (float*)d_out;            // [n] unique ids (float), -1 padded
    float* out_feat = (float*)d_out + n;       // [n][C] scattered features

    unsigned* bm = (unsigned*)d_ws;            // bitmask, W words
    unsigned* dup = bm + W;                    // duplicate bitmask, W words
    unsigned* wp = dup + W;                    // word prefix (block-local), W words
    unsigned* bs = wp + W;                     // block sums + total, SCAN_NB+1 words
    unsigned* lin = bs + SCAN_NB + 63;         // per-point linear id, n words

    // zero bitmask + dup bitmask (2 MB)
    zero_ws<<<(2 * W) / (4 * 256), 256, 0, stream>>>((uint4*)bm);

    mark_bits<<<(n + 255) / 256, 256, 0, stream>>>(coords, bm, dup, lin, n);
    scan1<<<SCAN_NB, SCAN_BS, 0, stream>>>(bm, wp, bs);
    scan2<<<1, SCAN_NB, 0, stream>>>(bs);
    emit_uniq<<<W / 256, 256, 0, stream>>>(bm, wp, bs, out_ids);
    tail_fill<<<(n * 16 + 255) / 256, 256, 0, stream>>>(out_ids, out_feat, bs, n);
    zero_dup<<<W / 256, 256, 0, stream>>>(bm, dup, wp, bs, out_feat);

    int scatter_threads = n * 16;  // one float4 per thread
    scatter_feat<<<(scatter_threads + 255) / 256, 256, 0, stream>>>(
        lin, (const floatx4*)feat, bm, dup, wp, bs, out_feat, n);
}